// Round 15
// baseline (6435.258 us; speedup 1.0000x reference)
//
#include <hip/hip_runtime.h>
#include <hip/hip_bf16.h>

#define S_LEN 16384
#define N_IN 23
#define CH2 32
#define NCH2 (S_LEN / CH2)     // 512 chunks
#define RING_D 8               // ring slots per stage

typedef float v2f __attribute__((ext_vector_type(2)));
typedef _Float16 h2v __attribute__((ext_vector_type(2)));

// ---------------- fast activations (v_exp_f32 + v_rcp_f32) ----------------
__device__ __forceinline__ float fsig(float x) {
    return __builtin_amdgcn_rcpf(1.f + __expf(-x));   // exp(+inf)->inf, rcp(inf)->0: safe
}
__device__ __forceinline__ float ftanh_fast(float x) {
    float e = __expf(-2.f * fabsf(x));                // in (0,1]
    float r = (1.f - e) * __builtin_amdgcn_rcpf(1.f + e);
    return x >= 0.f ? r : -r;
}
// broadcast lane k's value of v to all lanes (VALU readlane, no LDS)
__device__ __forceinline__ float rlane(float v, int k) {
    return __uint_as_float(__builtin_amdgcn_readlane(__float_as_uint(v), k));
}
__device__ __forceinline__ h2v rlane_h2(h2v v, int k) {
    int b;
    __builtin_memcpy(&b, &v, 4);
    b = __builtin_amdgcn_readlane(b, k);
    h2v r;
    __builtin_memcpy(&r, &b, 4);
    return r;
}
__device__ __forceinline__ h2v pack_h2(float a, float b) {
    auto p = __builtin_amdgcn_cvt_pkrtz(a, b);   // __fp16 ext_vector(2)
    h2v r;
    __builtin_memcpy(&r, &p, 4);                 // same bits, different elt type
    return r;
}

#if __has_builtin(__builtin_amdgcn_fdot2)
__device__ __forceinline__ float fdot2_hw(h2v w, h2v h, float acc) {
    return __builtin_amdgcn_fdot2(w, h, acc, false);
}
#define FDOT2(w, h, acc) fdot2_hw((w), (h), (acc))
#else
__device__ __forceinline__ float fdot2_sw(h2v w, h2v h, float acc) {
    return acc + (float)w.x * (float)h.x + (float)w.y * (float)h.y;
}
#define FDOT2(w, h, acc) fdot2_sw((w), (h), (acc))
#endif

// ---------------- dtype autodetect (bf16 vs fp32 input buffers) ----------------
__global__ void detect_kernel(const void* probe, int nsamp, int* flag)
{
    if (blockIdx.x == 0 && threadIdx.x == 0) {
        const unsigned short* p = (const unsigned short*)probe;
        int isbf16 = 1;
        for (int i = 0; i < nsamp; i++) {
            float v = __uint_as_float(((unsigned int)p[i]) << 16);
            if (!(fabsf(v) < 1e4f)) { isbf16 = 0; break; }
        }
        *flag = isbf16;
    }
}

// ---------------- ingest: convert all inputs to fp32 in ws ----------------
struct IngestArgs {
    const void* src[N_IN];
    float*      dst[N_IN];
    int         n[N_IN];
};

__global__ void ingest_kernel(IngestArgs args, const int* __restrict__ flag)
{
    const int isbf16 = *flag;
    const int tid    = blockIdx.x * blockDim.x + threadIdx.x;
    const int stride = gridDim.x * blockDim.x;
    for (int i = 0; i < N_IN; i++) {
        const int n = args.n[i];
        float* dst  = args.dst[i];
        if (isbf16) {
            const unsigned short* s = (const unsigned short*)args.src[i];
            for (int j = tid; j < n; j += stride)
                dst[j] = __uint_as_float(((unsigned int)s[j]) << 16);
        } else {
            const float* s = (const float*)args.src[i];
            for (int j = tid; j < n; j += stride)
                dst[j] = s[j];
        }
    }
}

// ---------------- zero the progress flags (ws is poisoned each launch) --------
__global__ void init_kernel(int* prog)
{
    int t = threadIdx.x;
    if (t < 1024) prog[t] = 0;
}

// ---------------- fc1 + fc2 (parallel) ----------------
__global__ void fc12_kernel(const float* __restrict__ x,
                            const float* __restrict__ W1, const float* __restrict__ b1,
                            const float* __restrict__ W2, const float* __restrict__ b2,
                            float* __restrict__ h2out)
{
    int s = blockIdx.x * blockDim.x + threadIdx.x;
    if (s >= S_LEN) return;
    float xin[6];
#pragma unroll
    for (int k = 0; k < 6; k++) xin[k] = x[s * 6 + k];
    float h1[20];
#pragma unroll
    for (int j = 0; j < 20; j++) {
        float a = b1[j];
#pragma unroll
        for (int k = 0; k < 6; k++) a += W1[j * 6 + k] * xin[k];
        h1[j] = a > 0.f ? a : 0.f;
    }
#pragma unroll
    for (int j = 0; j < 20; j++) {
        float a = b2[j];
#pragma unroll
        for (int k = 0; k < 20; k++) a += W2[j * 20 + k] * h1[k];
        h2out[s * 20 + j] = a > 0.f ? a : 0.f;
    }
}

// =========== producer: xw[s,g] = bih[g]+bhh[g] + Wih[g,:].in[s,:], chunked ====
// Register-tiled GEMM, 256 threads. TRANS: write cell-major [sl][cell][part]
// (part = gate i/f/g/o) so the scan reads one float4 per cell per step.
template <int DIN, int NG, bool TRANS>
__device__ void producer_block(const float* __restrict__ in,    // [S, DIN]
                               const float* __restrict__ Wih,   // [NG, DIN]
                               const float* __restrict__ bih,
                               const float* __restrict__ bhh,
                               float* __restrict__ ring,        // [RING_D][CH2*NG]
                               int* my_prog, int* in_prog, int* cons_prog,
                               float* smem)
{
    constexpr int GR  = NG / 3;      // row groups
    constexpr int GS  = 256 / GR;    // sl groups
    constexpr int SLT = CH2 / GS;    // sl per thread

    const int t  = threadIdx.x;
    const int rg = t % GR;
    const int sg = t / GR;

    float* in_sh = smem;             // CH2*DIN
    float* xw_sh = smem + CH2 * DIN; // CH2*NG

    float w[3][DIN];
    float bs[3];
    int cellr[3], partr[3];
#pragma unroll
    for (int r = 0; r < 3; r++) {
        const int row = rg * 3 + r;
#pragma unroll
        for (int k = 0; k < DIN; k++) w[r][k] = Wih[row * DIN + k];
        bs[r] = bih[row] + bhh[row];
        cellr[r] = row % 48;
        partr[r] = row / 48;
    }

    const float4* x4 = (const float4*)in_sh;

    for (int c = 0; c < NCH2; c++) {
        if (t == 0) {
            if (in_prog) {
                while (__hip_atomic_load(in_prog, __ATOMIC_ACQUIRE, __HIP_MEMORY_SCOPE_AGENT) < c + 1)
                    __builtin_amdgcn_s_sleep(1);
            }
            if (c >= RING_D) {  // don't overwrite a slot the consumer hasn't used
                while (__hip_atomic_load(cons_prog, __ATOMIC_ACQUIRE, __HIP_MEMORY_SCOPE_AGENT) < c - RING_D + 1)
                    __builtin_amdgcn_s_sleep(1);
            }
        }
        __syncthreads();
        {   // input chunk -> LDS
            const float4* gsrc = (const float4*)(in + (size_t)c * CH2 * DIN);
            float4* ldst = (float4*)in_sh;
            for (int i = t; i < CH2 * DIN / 4; i += 256) ldst[i] = gsrc[i];
        }
        __syncthreads();

#pragma unroll
        for (int i = 0; i < SLT; i++) {
            const int sl = sg * SLT + i;
            float a0 = bs[0], a1 = bs[1], a2 = bs[2];
#pragma unroll
            for (int k = 0; k < DIN / 4; k++) {
                float4 xv = x4[sl * (DIN / 4) + k];
                a0 += w[0][4 * k + 0] * xv.x; a0 += w[0][4 * k + 1] * xv.y;
                a0 += w[0][4 * k + 2] * xv.z; a0 += w[0][4 * k + 3] * xv.w;
                a1 += w[1][4 * k + 0] * xv.x; a1 += w[1][4 * k + 1] * xv.y;
                a1 += w[1][4 * k + 2] * xv.z; a1 += w[1][4 * k + 3] * xv.w;
                a2 += w[2][4 * k + 0] * xv.x; a2 += w[2][4 * k + 1] * xv.y;
                a2 += w[2][4 * k + 2] * xv.z; a2 += w[2][4 * k + 3] * xv.w;
            }
            if (TRANS) {
                xw_sh[(sl * 48 + cellr[0]) * 4 + partr[0]] = a0;
                xw_sh[(sl * 48 + cellr[1]) * 4 + partr[1]] = a1;
                xw_sh[(sl * 48 + cellr[2]) * 4 + partr[2]] = a2;
            } else {
                xw_sh[sl * NG + rg * 3 + 0] = a0;
                xw_sh[sl * NG + rg * 3 + 1] = a1;
                xw_sh[sl * NG + rg * 3 + 2] = a2;
            }
        }
        __syncthreads();
        {   // xw chunk -> ring slot
            const float4* lsrc = (const float4*)xw_sh;
            float4* gdst = (float4*)(ring + (size_t)(c % RING_D) * CH2 * NG);
            for (int i = t; i < CH2 * NG / 4; i += 256) gdst[i] = lsrc[i];
        }
        __syncthreads();   // drain vmcnt before publishing
        if (t == 0)
            __hip_atomic_store(my_prog, c + 1, __ATOMIC_RELEASE, __HIP_MEMORY_SCOPE_AGENT);
    }
}

// =========== LSTM scan: single wave all-4-gates f16, wave-specialized block ===
// Wave 0: barrier-free scan within a chunk (lane j owns cell j; 96 h2v weight
//   regs; 24 rlane + 96 fdot2 per step in 16 accumulators x 6-deep chains).
// Wave 1: stores chunk c-1's h (double-buffered LDS) + publishes progress.
// Waves 2-3: spin on producer flag (off scan's path) + stage ring slot c+1
//   into the other parity xw LDS buffer. ONE barrier per 32 steps.
__device__ void lstm_scan(const float* __restrict__ Whh,     // [192, 48]
                          const float* __restrict__ ring,    // [RING_D][CH2*192] cell-major
                          float* __restrict__ hseq,          // [S, 48]
                          int* my_prog, int* prod_prog, float* smem)
{
    const int t = threadIdx.x;
    const int j = (t < 48) ? t : 47;      // lanes 48..63 shadow cell 47 (no store)
    float* xw_buf = smem;                 // 2 * CH2*192 = 12288
    float* hh_buf = smem + 12288;         // 2 * CH2*48  = 3072

    h2v wI[24], wF[24], wG[24], wO[24];   // 96 VGPRs of f16-packed Whh rows
    if (t < 64) {
#pragma unroll
        for (int k = 0; k < 24; k++) {
            wI[k] = pack_h2(Whh[j * 48 + 2 * k],         Whh[j * 48 + 2 * k + 1]);
            wF[k] = pack_h2(Whh[(48 + j) * 48 + 2 * k],  Whh[(48 + j) * 48 + 2 * k + 1]);
            wG[k] = pack_h2(Whh[(96 + j) * 48 + 2 * k],  Whh[(96 + j) * 48 + 2 * k + 1]);
            wO[k] = pack_h2(Whh[(144 + j) * 48 + 2 * k], Whh[(144 + j) * 48 + 2 * k + 1]);
        }
    }
    float hvec = 0.f, ccell = 0.f;

    // prologue: waves 2-3 stage slot 0 into buffer 0
    if (t >= 128) {
        while (__hip_atomic_load(prod_prog, __ATOMIC_ACQUIRE, __HIP_MEMORY_SCOPE_AGENT) < 1)
            __builtin_amdgcn_s_sleep(8);
        const float4* g = (const float4*)ring;
        float4* d = (float4*)xw_buf;
        for (int i = t - 128; i < CH2 * 48; i += 128) d[i] = g[i];
    }
    __syncthreads();

    for (int c = 0; c < NCH2; c++) {
        if (t < 64) {
            // ---- scan wave: 32 steps, zero barriers, zero exchange ----
            const float4* xf = (const float4*)(xw_buf + (c & 1) * (CH2 * 192));
            float* hh = hh_buf + (c & 1) * (CH2 * 48);
            float4 xw4 = xf[j];
            for (int sl = 0; sl < CH2; sl++) {
                float4 nxt = xf[(sl + 1 < CH2 ? sl + 1 : sl) * 48 + j];   // prefetch
                float hn = __shfl_down(hvec, 1, 64);
                h2v hp = pack_h2(hvec, hn);
                // 16 accumulators, 6-deep fdot2 chains (shorter serial chain)
                float aI0 = xw4.x, aF0 = xw4.y, aG0 = xw4.z, aO0 = xw4.w;
                float aI1 = 0.f, aF1 = 0.f, aG1 = 0.f, aO1 = 0.f;
                float aI2 = 0.f, aF2 = 0.f, aG2 = 0.f, aO2 = 0.f;
                float aI3 = 0.f, aF3 = 0.f, aG3 = 0.f, aO3 = 0.f;
#pragma unroll
                for (int kp = 0; kp < 6; kp++) {
                    h2v hb = rlane_h2(hp, 2 * kp);
                    aI0 = FDOT2(wI[kp], hb, aI0);
                    aF0 = FDOT2(wF[kp], hb, aF0);
                    aG0 = FDOT2(wG[kp], hb, aG0);
                    aO0 = FDOT2(wO[kp], hb, aO0);
                }
#pragma unroll
                for (int kp = 6; kp < 12; kp++) {
                    h2v hb = rlane_h2(hp, 2 * kp);
                    aI1 = FDOT2(wI[kp], hb, aI1);
                    aF1 = FDOT2(wF[kp], hb, aF1);
                    aG1 = FDOT2(wG[kp], hb, aG1);
                    aO1 = FDOT2(wO[kp], hb, aO1);
                }
#pragma unroll
                for (int kp = 12; kp < 18; kp++) {
                    h2v hb = rlane_h2(hp, 2 * kp);
                    aI2 = FDOT2(wI[kp], hb, aI2);
                    aF2 = FDOT2(wF[kp], hb, aF2);
                    aG2 = FDOT2(wG[kp], hb, aG2);
                    aO2 = FDOT2(wO[kp], hb, aO2);
                }
#pragma unroll
                for (int kp = 18; kp < 24; kp++) {
                    h2v hb = rlane_h2(hp, 2 * kp);
                    aI3 = FDOT2(wI[kp], hb, aI3);
                    aF3 = FDOT2(wF[kp], hb, aF3);
                    aG3 = FDOT2(wG[kp], hb, aG3);
                    aO3 = FDOT2(wO[kp], hb, aO3);
                }
                float iv = fsig((aI0 + aI1) + (aI2 + aI3));
                float fv = fsig((aF0 + aF1) + (aF2 + aF3));
                float gv = 2.f * fsig(2.f * ((aG0 + aG1) + (aG2 + aG3))) - 1.f;
                float ov = fsig((aO0 + aO1) + (aO2 + aO3));
                ccell = fv * ccell + iv * gv;
                float h = ov * ftanh_fast(ccell);
                hvec = h;
                if (t < 48) hh[sl * 48 + t] = h;
                xw4 = nxt;
            }
        } else if (t < 128) {
            // ---- wave 1: store chunk c-1's h, publish progress ----
            if (c >= 1) {
                const float4* s4 = (const float4*)(hh_buf + ((c - 1) & 1) * (CH2 * 48));
                float4* d4 = (float4*)(hseq + (size_t)(c - 1) * CH2 * 48);
                for (int i = t - 64; i < CH2 * 12; i += 64) d4[i] = s4[i];
                if (t == 64)   // release: wave-level vmcnt drain covers all lanes' stores
                    __hip_atomic_store(my_prog, c, __ATOMIC_RELEASE, __HIP_MEMORY_SCOPE_AGENT);
            }
        } else {
            // ---- waves 2-3: stage ring slot c+1 into the other parity buffer ----
            if (c + 1 < NCH2) {
                while (__hip_atomic_load(prod_prog, __ATOMIC_ACQUIRE, __HIP_MEMORY_SCOPE_AGENT) < c + 2)
                    __builtin_amdgcn_s_sleep(8);
                const float4* g = (const float4*)(ring + (size_t)((c + 1) % RING_D) * CH2 * 192);
                float4* d = (float4*)(xw_buf + ((c + 1) & 1) * (CH2 * 192));
                for (int i = t - 128; i < CH2 * 48; i += 128) d[i] = g[i];
            }
        }
        __syncthreads();   // the ONLY barrier per 32 steps
    }
    // epilogue: store the final chunk's h
    if (t >= 64 && t < 128) {
        const float4* s4 = (const float4*)(hh_buf + ((NCH2 - 1) & 1) * (CH2 * 48));
        float4* d4 = (float4*)(hseq + (size_t)(NCH2 - 1) * CH2 * 48);
        for (int i = t - 64; i < CH2 * 12; i += 64) d4[i] = s4[i];
        if (t == 64)
            __hip_atomic_store(my_prog, NCH2, __ATOMIC_RELEASE, __HIP_MEMORY_SCOPE_AGENT);
    }
}

// =========== tanh-RNN scan: same wave-specialized pattern =====================
__device__ void rnn_scan(const float* __restrict__ Whh,      // [24, 24]
                         const float* __restrict__ ring,     // [RING_D][CH2*24]
                         float* __restrict__ hseq,           // [S, 24]
                         int* my_prog, int* prod_prog, float* smem)
{
    const int t = threadIdx.x;
    float* xw_buf = smem;                 // 2 * 768
    float* hh_buf = smem + 1536;          // 2 * 768

    float whh[24];
    if (t < 24) {
#pragma unroll
        for (int k = 0; k < 24; k++) whh[k] = Whh[t * 24 + k];
    }
    float hvec = 0.f;

    if (t >= 128) {
        while (__hip_atomic_load(prod_prog, __ATOMIC_ACQUIRE, __HIP_MEMORY_SCOPE_AGENT) < 1)
            __builtin_amdgcn_s_sleep(8);
        const float4* g = (const float4*)ring;
        float4* d = (float4*)xw_buf;
        for (int i = t - 128; i < CH2 * 6; i += 128) d[i] = g[i];
    }
    __syncthreads();

    for (int c = 0; c < NCH2; c++) {
        if (t < 64) {
            const float* xwc = xw_buf + (c & 1) * (CH2 * 24);
            float* hh = hh_buf + (c & 1) * (CH2 * 24);
            float xwv = (t < 24) ? xwc[t] : 0.f;
            for (int sl = 0; sl < CH2; sl++) {
                float nxtx = (t < 24) ? xwc[((sl + 1 < CH2) ? sl + 1 : sl) * 24 + t] : 0.f;
                float a0 = xwv, a1 = 0.f, a2 = 0.f, a3 = 0.f;
#pragma unroll
                for (int k = 0; k < 24; k += 4) {
                    a0 += rlane(hvec, k + 0) * whh[k + 0];
                    a1 += rlane(hvec, k + 1) * whh[k + 1];
                    a2 += rlane(hvec, k + 2) * whh[k + 2];
                    a3 += rlane(hvec, k + 3) * whh[k + 3];
                }
                float h = ftanh_fast((a0 + a1) + (a2 + a3));
                if (t < 24) {
                    hvec = h;
                    hh[sl * 24 + t] = h;
                }
                xwv = nxtx;
            }
        } else if (t < 128) {
            if (c >= 1) {
                const float4* s4 = (const float4*)(hh_buf + ((c - 1) & 1) * (CH2 * 24));
                float4* d4 = (float4*)(hseq + (size_t)(c - 1) * CH2 * 24);
                for (int i = t - 64; i < CH2 * 6; i += 64) d4[i] = s4[i];
                if (t == 64)
                    __hip_atomic_store(my_prog, c, __ATOMIC_RELEASE, __HIP_MEMORY_SCOPE_AGENT);
            }
        } else {
            if (c + 1 < NCH2) {
                while (__hip_atomic_load(prod_prog, __ATOMIC_ACQUIRE, __HIP_MEMORY_SCOPE_AGENT) < c + 2)
                    __builtin_amdgcn_s_sleep(8);
                const float4* g = (const float4*)(ring + (size_t)((c + 1) % RING_D) * CH2 * 24);
                float4* d = (float4*)(xw_buf + ((c + 1) & 1) * (CH2 * 24));
                for (int i = t - 128; i < CH2 * 6; i += 128) d[i] = g[i];
            }
        }
        __syncthreads();
    }
    if (t >= 64 && t < 128) {
        const float4* s4 = (const float4*)(hh_buf + ((NCH2 - 1) & 1) * (CH2 * 24));
        float4* d4 = (float4*)(hseq + (size_t)(NCH2 - 1) * CH2 * 24);
        for (int i = t - 64; i < CH2 * 6; i += 64) d4[i] = s4[i];
        if (t == 64)
            __hip_atomic_store(my_prog, NCH2, __ATOMIC_RELEASE, __HIP_MEMORY_SCOPE_AGENT);
    }
}

// ---------------- the 14-block pipeline megakernel ----------------
struct PipeArgs {
    const float* h2;
    const float* l0_Wih; const float* l0_Whh; const float* l0_bih; const float* l0_bhh;
    const float* lr_Wih; const float* lr_Whh; const float* lr_bih; const float* lr_bhh;
    const float* r0_Wih; const float* r0_Whh; const float* r0_bih; const float* r0_bhh;
    const float* r1_Wih; const float* r1_Whh; const float* r1_bih; const float* r1_bhh;
    float* seq0; float* seq1; float* seq2; float* seq3; float* seq4;
    float* rnnA; float* rnnB;
    float* ring[7];   // xw rings per stage
    int* prog;        // scan l: prog[l*64]; producer l: prog[(8+l)*64]
};

__global__ void __launch_bounds__(256, 1) pipeline_kernel(PipeArgs a)
{
    __shared__ __align__(16) float smem[15360];   // 61.4 KiB (LSTM scan worst case)
    const int b = blockIdx.x;
    const float* seqin[7] = {a.h2, a.seq0, a.seq1, a.seq2, a.seq3, a.seq4, a.rnnA};
    float* seqout[7] = {a.seq0, a.seq1, a.seq2, a.seq3, a.seq4, a.rnnA, a.rnnB};
    int* sp[7]; int* pp[7];
    for (int l = 0; l < 7; l++) { sp[l] = a.prog + l * 64; pp[l] = a.prog + (8 + l) * 64; }

    if (b < 7) {
        // ---- producers ----
        const int l = b;
        int* inp = (l == 0) ? nullptr : sp[l - 1];
        if (l == 0) {
            producer_block<20, 192, true>(a.h2, a.l0_Wih, a.l0_bih, a.l0_bhh,
                                          a.ring[0], pp[0], inp, sp[0], smem);
        } else if (l <= 4) {
            producer_block<48, 192, true>(seqin[l],
                                          a.lr_Wih + (size_t)(l - 1) * 192 * 48,
                                          a.lr_bih + (size_t)(l - 1) * 192,
                                          a.lr_bhh + (size_t)(l - 1) * 192,
                                          a.ring[l], pp[l], inp, sp[l], smem);
        } else if (l == 5) {
            producer_block<48, 24, false>(a.seq4, a.r0_Wih, a.r0_bih, a.r0_bhh,
                                          a.ring[5], pp[5], inp, sp[5], smem);
        } else {
            producer_block<24, 24, false>(a.rnnA, a.r1_Wih, a.r1_bih, a.r1_bhh,
                                          a.ring[6], pp[6], inp, sp[6], smem);
        }
    } else {
        // ---- scans ----
        const int l = b - 7;
        if (l == 0) {
            lstm_scan(a.l0_Whh, a.ring[0], seqout[0], sp[0], pp[0], smem);
        } else if (l <= 4) {
            lstm_scan(a.lr_Whh + (size_t)(l - 1) * 192 * 48,
                      a.ring[l], seqout[l], sp[l], pp[l], smem);
        } else if (l == 5) {
            rnn_scan(a.r0_Whh, a.ring[5], seqout[5], sp[5], pp[5], smem);
        } else {
            rnn_scan(a.r1_Whh, a.ring[6], seqout[6], sp[6], pp[6], smem);
        }
    }
}

// ---------------- epilogue: relu + fc4, bf16 or fp32 out per flag ----------------
__global__ void out_kernel(const float* __restrict__ hin,
                           const float* __restrict__ W,  // [2, 24]
                           const float* __restrict__ b,  // [2]
                           void* __restrict__ out,
                           const int* __restrict__ flag)
{
    int s = blockIdx.x * blockDim.x + threadIdx.x;
    if (s >= S_LEN) return;
    const int isbf16 = *flag;
    float h[24];
#pragma unroll
    for (int k = 0; k < 24; k++) {
        float v = hin[s * 24 + k];
        h[k] = v > 0.f ? v : 0.f;
    }
#pragma unroll
    for (int j = 0; j < 2; j++) {
        float a = b[j];
#pragma unroll
        for (int k = 0; k < 24; k++) a += W[j * 24 + k] * h[k];
        if (isbf16) ((__hip_bfloat16*)out)[s * 2 + j] = __float2bfloat16(a);
        else        ((float*)out)[s * 2 + j] = a;
    }
}

extern "C" void kernel_launch(void* const* d_in, const int* in_sizes, int n_in,
                              void* d_out, int out_size, void* d_ws, size_t ws_size,
                              hipStream_t stream)
{
    // ---- workspace layout (floats from ws base) ----
    int*   ip    = (int*)d_ws;        // [0]: dtype flag; [256..1280): progress slots
    int*   flag  = ip;
    int*   prog  = ip + 256;
    float* ws    = (float*)d_ws;
    float* conv0 = ws + 4096;

    IngestArgs ia;
    float* conv[N_IN];
    {
        float* p = conv0;
        for (int i = 0; i < N_IN; i++) {
            conv[i] = p;
            ia.src[i] = d_in[i];
            ia.dst[i] = p;
            ia.n[i]   = in_sizes[i];
            p += in_sizes[i];
        }
    }
    float* h2   = conv0 + 191000;       // [S,20]  327,680
    float* seq0 = h2 + 327680;          // 5 x [S,48]
    float* seq1 = seq0 + 786432;
    float* seq2 = seq1 + 786432;
    float* seq3 = seq2 + 786432;
    float* seq4 = seq3 + 786432;
    float* rnnA = seq4 + 786432;        // [S,24]
    float* rnnB = rnnA + 393216;        // [S,24]
    float* rbase = rnnB + 393216;       // rings
    float* ring[7];
    {
        float* p = rbase;
        for (int l = 0; l < 5; l++) { ring[l] = p; p += RING_D * CH2 * 192; }  // 49,152 ea
        for (int l = 5; l < 7; l++) { ring[l] = p; p += RING_D * CH2 * 24;  }  // 6,144 ea
    }

    const int TPB = 256;
    const int NB  = S_LEN / TPB;  // 64

    detect_kernel<<<1, 64, 0, stream>>>(d_in[1], in_sizes[1], flag);
    ingest_kernel<<<128, 256, 0, stream>>>(ia, flag);
    init_kernel<<<1, 1024, 0, stream>>>(prog);

    fc12_kernel<<<NB, TPB, 0, stream>>>(conv[0], conv[1], conv[2], conv[3], conv[4], h2);

    PipeArgs pa;
    pa.h2 = h2;
    pa.l0_Wih = conv[5];  pa.l0_Whh = conv[6];  pa.l0_bih = conv[7];  pa.l0_bhh = conv[8];
    pa.lr_Wih = conv[9];  pa.lr_Whh = conv[10]; pa.lr_bih = conv[11]; pa.lr_bhh = conv[12];
    pa.r0_Wih = conv[13]; pa.r0_Whh = conv[14]; pa.r0_bih = conv[15]; pa.r0_bhh = conv[16];
    pa.r1_Wih = conv[17]; pa.r1_Whh = conv[18]; pa.r1_bih = conv[19]; pa.r1_bhh = conv[20];
    pa.seq0 = seq0; pa.seq1 = seq1; pa.seq2 = seq2; pa.seq3 = seq3; pa.seq4 = seq4;
    pa.rnnA = rnnA; pa.rnnB = rnnB;
    for (int l = 0; l < 7; l++) pa.ring[l] = ring[l];
    pa.prog = prog;

    pipeline_kernel<<<14, 256, 0, stream>>>(pa);

    out_kernel<<<NB, TPB, 0, stream>>>(rnnB, conv[21], conv[22], d_out, flag);
}

// Round 16
// 6062.251 us; speedup vs baseline: 1.0615x; 1.0615x over previous
//
#include <hip/hip_runtime.h>
#include <hip/hip_bf16.h>

#define S_LEN 16384
#define N_IN 23
#define CH2 32
#define NCH2 (S_LEN / CH2)     // 512 chunks
#define RING_D 8               // ring slots per stage

typedef float v2f __attribute__((ext_vector_type(2)));
typedef _Float16 h2v __attribute__((ext_vector_type(2)));

// ---------------- fast activations (v_exp_f32 + v_rcp_f32) ----------------
__device__ __forceinline__ float fsig(float x) {
    return __builtin_amdgcn_rcpf(1.f + __expf(-x));   // exp(+inf)->inf, rcp(inf)->0: safe
}
__device__ __forceinline__ float ftanh_fast(float x) {
    float e = __expf(-2.f * fabsf(x));                // in (0,1]
    float r = (1.f - e) * __builtin_amdgcn_rcpf(1.f + e);
    return x >= 0.f ? r : -r;
}
// broadcast lane k's value of v to all lanes (VALU readlane, no LDS)
__device__ __forceinline__ float rlane(float v, int k) {
    return __uint_as_float(__builtin_amdgcn_readlane(__float_as_uint(v), k));
}
__device__ __forceinline__ h2v rlane_h2(h2v v, int k) {
    int b;
    __builtin_memcpy(&b, &v, 4);
    b = __builtin_amdgcn_readlane(b, k);
    h2v r;
    __builtin_memcpy(&r, &b, 4);
    return r;
}
__device__ __forceinline__ h2v pack_h2(float a, float b) {
    auto p = __builtin_amdgcn_cvt_pkrtz(a, b);   // __fp16 ext_vector(2)
    h2v r;
    __builtin_memcpy(&r, &p, 4);                 // same bits, different elt type
    return r;
}

#if __has_builtin(__builtin_amdgcn_fdot2)
__device__ __forceinline__ float fdot2_hw(h2v w, h2v h, float acc) {
    return __builtin_amdgcn_fdot2(w, h, acc, false);
}
#define FDOT2(w, h, acc) fdot2_hw((w), (h), (acc))
#else
__device__ __forceinline__ float fdot2_sw(h2v w, h2v h, float acc) {
    return acc + (float)w.x * (float)h.x + (float)w.y * (float)h.y;
}
#define FDOT2(w, h, acc) fdot2_sw((w), (h), (acc))
#endif

// ---------------- dtype autodetect (bf16 vs fp32 input buffers) ----------------
__global__ void detect_kernel(const void* probe, int nsamp, int* flag)
{
    if (blockIdx.x == 0 && threadIdx.x == 0) {
        const unsigned short* p = (const unsigned short*)probe;
        int isbf16 = 1;
        for (int i = 0; i < nsamp; i++) {
            float v = __uint_as_float(((unsigned int)p[i]) << 16);
            if (!(fabsf(v) < 1e4f)) { isbf16 = 0; break; }
        }
        *flag = isbf16;
    }
}

// ---------------- ingest: convert all inputs to fp32 in ws ----------------
struct IngestArgs {
    const void* src[N_IN];
    float*      dst[N_IN];
    int         n[N_IN];
};

__global__ void ingest_kernel(IngestArgs args, const int* __restrict__ flag)
{
    const int isbf16 = *flag;
    const int tid    = blockIdx.x * blockDim.x + threadIdx.x;
    const int stride = gridDim.x * blockDim.x;
    for (int i = 0; i < N_IN; i++) {
        const int n = args.n[i];
        float* dst  = args.dst[i];
        if (isbf16) {
            const unsigned short* s = (const unsigned short*)args.src[i];
            for (int j = tid; j < n; j += stride)
                dst[j] = __uint_as_float(((unsigned int)s[j]) << 16);
        } else {
            const float* s = (const float*)args.src[i];
            for (int j = tid; j < n; j += stride)
                dst[j] = s[j];
        }
    }
}

// ---------------- zero the progress flags (ws is poisoned each launch) --------
__global__ void init_kernel(int* prog)
{
    int t = threadIdx.x;
    if (t < 1024) prog[t] = 0;
}

// ---------------- fc1 + fc2 (parallel) ----------------
__global__ void fc12_kernel(const float* __restrict__ x,
                            const float* __restrict__ W1, const float* __restrict__ b1,
                            const float* __restrict__ W2, const float* __restrict__ b2,
                            float* __restrict__ h2out)
{
    int s = blockIdx.x * blockDim.x + threadIdx.x;
    if (s >= S_LEN) return;
    float xin[6];
#pragma unroll
    for (int k = 0; k < 6; k++) xin[k] = x[s * 6 + k];
    float h1[20];
#pragma unroll
    for (int j = 0; j < 20; j++) {
        float a = b1[j];
#pragma unroll
        for (int k = 0; k < 6; k++) a += W1[j * 6 + k] * xin[k];
        h1[j] = a > 0.f ? a : 0.f;
    }
#pragma unroll
    for (int j = 0; j < 20; j++) {
        float a = b2[j];
#pragma unroll
        for (int k = 0; k < 20; k++) a += W2[j * 20 + k] * h1[k];
        h2out[s * 20 + j] = a > 0.f ? a : 0.f;
    }
}

// =========== producer: xw[s,g] = bih[g]+bhh[g] + Wih[g,:].in[s,:], chunked ====
// Register-tiled GEMM, 256 threads. TRANS: write cell-major [sl][cell][part]
// (part = gate i/f/g/o) so the scan reads one float4 per cell per step.
template <int DIN, int NG, bool TRANS>
__device__ void producer_block(const float* __restrict__ in,    // [S, DIN]
                               const float* __restrict__ Wih,   // [NG, DIN]
                               const float* __restrict__ bih,
                               const float* __restrict__ bhh,
                               float* __restrict__ ring,        // [RING_D][CH2*NG]
                               int* my_prog, int* in_prog, int* cons_prog,
                               float* smem)
{
    constexpr int GR  = NG / 3;      // row groups
    constexpr int GS  = 256 / GR;    // sl groups
    constexpr int SLT = CH2 / GS;    // sl per thread

    const int t  = threadIdx.x;
    const int rg = t % GR;
    const int sg = t / GR;

    float* in_sh = smem;             // CH2*DIN
    float* xw_sh = smem + CH2 * DIN; // CH2*NG

    float w[3][DIN];
    float bs[3];
    int cellr[3], partr[3];
#pragma unroll
    for (int r = 0; r < 3; r++) {
        const int row = rg * 3 + r;
#pragma unroll
        for (int k = 0; k < DIN; k++) w[r][k] = Wih[row * DIN + k];
        bs[r] = bih[row] + bhh[row];
        cellr[r] = row % 48;
        partr[r] = row / 48;
    }

    const float4* x4 = (const float4*)in_sh;

    for (int c = 0; c < NCH2; c++) {
        if (t == 0) {
            if (in_prog) {
                while (__hip_atomic_load(in_prog, __ATOMIC_ACQUIRE, __HIP_MEMORY_SCOPE_AGENT) < c + 1)
                    __builtin_amdgcn_s_sleep(1);
            }
            if (c >= RING_D) {  // don't overwrite a slot the consumer hasn't used
                while (__hip_atomic_load(cons_prog, __ATOMIC_ACQUIRE, __HIP_MEMORY_SCOPE_AGENT) < c - RING_D + 1)
                    __builtin_amdgcn_s_sleep(1);
            }
        }
        __syncthreads();
        {   // input chunk -> LDS
            const float4* gsrc = (const float4*)(in + (size_t)c * CH2 * DIN);
            float4* ldst = (float4*)in_sh;
            for (int i = t; i < CH2 * DIN / 4; i += 256) ldst[i] = gsrc[i];
        }
        __syncthreads();

#pragma unroll
        for (int i = 0; i < SLT; i++) {
            const int sl = sg * SLT + i;
            float a0 = bs[0], a1 = bs[1], a2 = bs[2];
#pragma unroll
            for (int k = 0; k < DIN / 4; k++) {
                float4 xv = x4[sl * (DIN / 4) + k];
                a0 += w[0][4 * k + 0] * xv.x; a0 += w[0][4 * k + 1] * xv.y;
                a0 += w[0][4 * k + 2] * xv.z; a0 += w[0][4 * k + 3] * xv.w;
                a1 += w[1][4 * k + 0] * xv.x; a1 += w[1][4 * k + 1] * xv.y;
                a1 += w[1][4 * k + 2] * xv.z; a1 += w[1][4 * k + 3] * xv.w;
                a2 += w[2][4 * k + 0] * xv.x; a2 += w[2][4 * k + 1] * xv.y;
                a2 += w[2][4 * k + 2] * xv.z; a2 += w[2][4 * k + 3] * xv.w;
            }
            if (TRANS) {
                xw_sh[(sl * 48 + cellr[0]) * 4 + partr[0]] = a0;
                xw_sh[(sl * 48 + cellr[1]) * 4 + partr[1]] = a1;
                xw_sh[(sl * 48 + cellr[2]) * 4 + partr[2]] = a2;
            } else {
                xw_sh[sl * NG + rg * 3 + 0] = a0;
                xw_sh[sl * NG + rg * 3 + 1] = a1;
                xw_sh[sl * NG + rg * 3 + 2] = a2;
            }
        }
        __syncthreads();
        {   // xw chunk -> ring slot
            const float4* lsrc = (const float4*)xw_sh;
            float4* gdst = (float4*)(ring + (size_t)(c % RING_D) * CH2 * NG);
            for (int i = t; i < CH2 * NG / 4; i += 256) gdst[i] = lsrc[i];
        }
        __syncthreads();   // drain vmcnt before publishing
        if (t == 0)
            __hip_atomic_store(my_prog, c + 1, __ATOMIC_RELEASE, __HIP_MEMORY_SCOPE_AGENT);
    }
}

// =========== LSTM scan: single wave all-4-gates f16, wave-specialized block ===
// Wave 0: barrier-free scan within a chunk (lane j owns cell j; 96 h2v weight
//   regs; 24 rlane + 96 fdot2 per step; h stays in lane registers).
// Wave 1: stores chunk c-1's h (double-buffered LDS) + publishes progress.
// Waves 2-3: spin on producer flag (off scan's path) + stage ring slot c+1
//   into the other parity xw LDS buffer. ONE barrier per 32 steps.
__device__ void lstm_scan(const float* __restrict__ Whh,     // [192, 48]
                          const float* __restrict__ ring,    // [RING_D][CH2*192] cell-major
                          float* __restrict__ hseq,          // [S, 48]
                          int* my_prog, int* prod_prog, float* smem)
{
    const int t = threadIdx.x;
    const int j = (t < 48) ? t : 47;      // lanes 48..63 shadow cell 47 (no store)
    float* xw_buf = smem;                 // 2 * CH2*192 = 12288
    float* hh_buf = smem + 12288;         // 2 * CH2*48  = 3072

    h2v wI[24], wF[24], wG[24], wO[24];   // 96 VGPRs of f16-packed Whh rows
    if (t < 64) {
#pragma unroll
        for (int k = 0; k < 24; k++) {
            wI[k] = pack_h2(Whh[j * 48 + 2 * k],         Whh[j * 48 + 2 * k + 1]);
            wF[k] = pack_h2(Whh[(48 + j) * 48 + 2 * k],  Whh[(48 + j) * 48 + 2 * k + 1]);
            wG[k] = pack_h2(Whh[(96 + j) * 48 + 2 * k],  Whh[(96 + j) * 48 + 2 * k + 1]);
            wO[k] = pack_h2(Whh[(144 + j) * 48 + 2 * k], Whh[(144 + j) * 48 + 2 * k + 1]);
        }
    }
    float hvec = 0.f, ccell = 0.f;

    // prologue: waves 2-3 stage slot 0 into buffer 0
    if (t >= 128) {
        while (__hip_atomic_load(prod_prog, __ATOMIC_ACQUIRE, __HIP_MEMORY_SCOPE_AGENT) < 1)
            __builtin_amdgcn_s_sleep(8);
        const float4* g = (const float4*)ring;
        float4* d = (float4*)xw_buf;
        for (int i = t - 128; i < CH2 * 48; i += 128) d[i] = g[i];
    }
    __syncthreads();

    for (int c = 0; c < NCH2; c++) {
        if (t < 64) {
            // ---- scan wave: 32 steps, zero barriers, zero exchange ----
            const float4* xf = (const float4*)(xw_buf + (c & 1) * (CH2 * 192));
            float* hh = hh_buf + (c & 1) * (CH2 * 48);
            float4 xw4 = xf[j];
            for (int sl = 0; sl < CH2; sl++) {
                float4 nxt = xf[(sl + 1 < CH2 ? sl + 1 : sl) * 48 + j];   // prefetch
                float hn = __shfl_down(hvec, 1, 64);
                h2v hp = pack_h2(hvec, hn);
                float aI0 = xw4.x, aF0 = xw4.y, aG0 = xw4.z, aO0 = xw4.w;
                float aI1 = 0.f, aF1 = 0.f, aG1 = 0.f, aO1 = 0.f;
#pragma unroll
                for (int kp = 0; kp < 12; kp++) {
                    h2v hb = rlane_h2(hp, 2 * kp);
                    aI0 = FDOT2(wI[kp], hb, aI0);
                    aF0 = FDOT2(wF[kp], hb, aF0);
                    aG0 = FDOT2(wG[kp], hb, aG0);
                    aO0 = FDOT2(wO[kp], hb, aO0);
                }
#pragma unroll
                for (int kp = 12; kp < 24; kp++) {
                    h2v hb = rlane_h2(hp, 2 * kp);
                    aI1 = FDOT2(wI[kp], hb, aI1);
                    aF1 = FDOT2(wF[kp], hb, aF1);
                    aG1 = FDOT2(wG[kp], hb, aG1);
                    aO1 = FDOT2(wO[kp], hb, aO1);
                }
                float iv = fsig(aI0 + aI1);
                float fv = fsig(aF0 + aF1);
                float gv = 2.f * fsig(2.f * (aG0 + aG1)) - 1.f;   // tanh, NaN-safe
                float ov = fsig(aO0 + aO1);
                ccell = fv * ccell + iv * gv;
                float h = ov * ftanh_fast(ccell);
                hvec = h;
                if (t < 48) hh[sl * 48 + t] = h;
                xw4 = nxt;
            }
        } else if (t < 128) {
            // ---- wave 1: store chunk c-1's h, publish progress ----
            if (c >= 1) {
                const float4* s4 = (const float4*)(hh_buf + ((c - 1) & 1) * (CH2 * 48));
                float4* d4 = (float4*)(hseq + (size_t)(c - 1) * CH2 * 48);
                for (int i = t - 64; i < CH2 * 12; i += 64) d4[i] = s4[i];
                if (t == 64)   // release: wave-level vmcnt drain covers all lanes' stores
                    __hip_atomic_store(my_prog, c, __ATOMIC_RELEASE, __HIP_MEMORY_SCOPE_AGENT);
            }
        } else {
            // ---- waves 2-3: stage ring slot c+1 into the other parity buffer ----
            if (c + 1 < NCH2) {
                while (__hip_atomic_load(prod_prog, __ATOMIC_ACQUIRE, __HIP_MEMORY_SCOPE_AGENT) < c + 2)
                    __builtin_amdgcn_s_sleep(8);
                const float4* g = (const float4*)(ring + (size_t)((c + 1) % RING_D) * CH2 * 192);
                float4* d = (float4*)(xw_buf + ((c + 1) & 1) * (CH2 * 192));
                for (int i = t - 128; i < CH2 * 48; i += 128) d[i] = g[i];
            }
        }
        __syncthreads();   // the ONLY barrier per 32 steps
    }
    // epilogue: store the final chunk's h
    if (t >= 64 && t < 128) {
        const float4* s4 = (const float4*)(hh_buf + ((NCH2 - 1) & 1) * (CH2 * 48));
        float4* d4 = (float4*)(hseq + (size_t)(NCH2 - 1) * CH2 * 48);
        for (int i = t - 64; i < CH2 * 12; i += 64) d4[i] = s4[i];
        if (t == 64)
            __hip_atomic_store(my_prog, NCH2, __ATOMIC_RELEASE, __HIP_MEMORY_SCOPE_AGENT);
    }
}

// =========== tanh-RNN scan: same wave-specialized pattern =====================
__device__ void rnn_scan(const float* __restrict__ Whh,      // [24, 24]
                         const float* __restrict__ ring,     // [RING_D][CH2*24]
                         float* __restrict__ hseq,           // [S, 24]
                         int* my_prog, int* prod_prog, float* smem)
{
    const int t = threadIdx.x;
    float* xw_buf = smem;                 // 2 * 768
    float* hh_buf = smem + 1536;          // 2 * 768

    float whh[24];
    if (t < 24) {
#pragma unroll
        for (int k = 0; k < 24; k++) whh[k] = Whh[t * 24 + k];
    }
    float hvec = 0.f;

    if (t >= 128) {
        while (__hip_atomic_load(prod_prog, __ATOMIC_ACQUIRE, __HIP_MEMORY_SCOPE_AGENT) < 1)
            __builtin_amdgcn_s_sleep(8);
        const float4* g = (const float4*)ring;
        float4* d = (float4*)xw_buf;
        for (int i = t - 128; i < CH2 * 6; i += 128) d[i] = g[i];
    }
    __syncthreads();

    for (int c = 0; c < NCH2; c++) {
        if (t < 64) {
            const float* xwc = xw_buf + (c & 1) * (CH2 * 24);
            float* hh = hh_buf + (c & 1) * (CH2 * 24);
            float xwv = (t < 24) ? xwc[t] : 0.f;
            for (int sl = 0; sl < CH2; sl++) {
                float nxtx = (t < 24) ? xwc[((sl + 1 < CH2) ? sl + 1 : sl) * 24 + t] : 0.f;
                float a0 = xwv, a1 = 0.f, a2 = 0.f, a3 = 0.f;
#pragma unroll
                for (int k = 0; k < 24; k += 4) {
                    a0 += rlane(hvec, k + 0) * whh[k + 0];
                    a1 += rlane(hvec, k + 1) * whh[k + 1];
                    a2 += rlane(hvec, k + 2) * whh[k + 2];
                    a3 += rlane(hvec, k + 3) * whh[k + 3];
                }
                float h = ftanh_fast((a0 + a1) + (a2 + a3));
                if (t < 24) {
                    hvec = h;
                    hh[sl * 24 + t] = h;
                }
                xwv = nxtx;
            }
        } else if (t < 128) {
            if (c >= 1) {
                const float4* s4 = (const float4*)(hh_buf + ((c - 1) & 1) * (CH2 * 24));
                float4* d4 = (float4*)(hseq + (size_t)(c - 1) * CH2 * 24);
                for (int i = t - 64; i < CH2 * 6; i += 64) d4[i] = s4[i];
                if (t == 64)
                    __hip_atomic_store(my_prog, c, __ATOMIC_RELEASE, __HIP_MEMORY_SCOPE_AGENT);
            }
        } else {
            if (c + 1 < NCH2) {
                while (__hip_atomic_load(prod_prog, __ATOMIC_ACQUIRE, __HIP_MEMORY_SCOPE_AGENT) < c + 2)
                    __builtin_amdgcn_s_sleep(8);
                const float4* g = (const float4*)(ring + (size_t)((c + 1) % RING_D) * CH2 * 24);
                float4* d = (float4*)(xw_buf + ((c + 1) & 1) * (CH2 * 24));
                for (int i = t - 128; i < CH2 * 6; i += 128) d[i] = g[i];
            }
        }
        __syncthreads();
    }
    if (t >= 64 && t < 128) {
        const float4* s4 = (const float4*)(hh_buf + ((NCH2 - 1) & 1) * (CH2 * 24));
        float4* d4 = (float4*)(hseq + (size_t)(NCH2 - 1) * CH2 * 24);
        for (int i = t - 64; i < CH2 * 6; i += 64) d4[i] = s4[i];
        if (t == 64)
            __hip_atomic_store(my_prog, NCH2, __ATOMIC_RELEASE, __HIP_MEMORY_SCOPE_AGENT);
    }
}

// ---------------- the 14-block pipeline megakernel ----------------
struct PipeArgs {
    const float* h2;
    const float* l0_Wih; const float* l0_Whh; const float* l0_bih; const float* l0_bhh;
    const float* lr_Wih; const float* lr_Whh; const float* lr_bih; const float* lr_bhh;
    const float* r0_Wih; const float* r0_Whh; const float* r0_bih; const float* r0_bhh;
    const float* r1_Wih; const float* r1_Whh; const float* r1_bih; const float* r1_bhh;
    float* seq0; float* seq1; float* seq2; float* seq3; float* seq4;
    float* rnnA; float* rnnB;
    float* ring[7];   // xw rings per stage
    int* prog;        // scan l: prog[l*64]; producer l: prog[(8+l)*64]
};

__global__ void __launch_bounds__(256, 1) pipeline_kernel(PipeArgs a)
{
    __shared__ __align__(16) float smem[15360];   // 61.4 KiB (LSTM scan worst case)
    const int b = blockIdx.x;
    const float* seqin[7] = {a.h2, a.seq0, a.seq1, a.seq2, a.seq3, a.seq4, a.rnnA};
    float* seqout[7] = {a.seq0, a.seq1, a.seq2, a.seq3, a.seq4, a.rnnA, a.rnnB};
    int* sp[7]; int* pp[7];
    for (int l = 0; l < 7; l++) { sp[l] = a.prog + l * 64; pp[l] = a.prog + (8 + l) * 64; }

    if (b < 7) {
        // ---- producers ----
        const int l = b;
        int* inp = (l == 0) ? nullptr : sp[l - 1];
        if (l == 0) {
            producer_block<20, 192, true>(a.h2, a.l0_Wih, a.l0_bih, a.l0_bhh,
                                          a.ring[0], pp[0], inp, sp[0], smem);
        } else if (l <= 4) {
            producer_block<48, 192, true>(seqin[l],
                                          a.lr_Wih + (size_t)(l - 1) * 192 * 48,
                                          a.lr_bih + (size_t)(l - 1) * 192,
                                          a.lr_bhh + (size_t)(l - 1) * 192,
                                          a.ring[l], pp[l], inp, sp[l], smem);
        } else if (l == 5) {
            producer_block<48, 24, false>(a.seq4, a.r0_Wih, a.r0_bih, a.r0_bhh,
                                          a.ring[5], pp[5], inp, sp[5], smem);
        } else {
            producer_block<24, 24, false>(a.rnnA, a.r1_Wih, a.r1_bih, a.r1_bhh,
                                          a.ring[6], pp[6], inp, sp[6], smem);
        }
    } else {
        // ---- scans ----
        const int l = b - 7;
        if (l == 0) {
            lstm_scan(a.l0_Whh, a.ring[0], seqout[0], sp[0], pp[0], smem);
        } else if (l <= 4) {
            lstm_scan(a.lr_Whh + (size_t)(l - 1) * 192 * 48,
                      a.ring[l], seqout[l], sp[l], pp[l], smem);
        } else if (l == 5) {
            rnn_scan(a.r0_Whh, a.ring[5], seqout[5], sp[5], pp[5], smem);
        } else {
            rnn_scan(a.r1_Whh, a.ring[6], seqout[6], sp[6], pp[6], smem);
        }
    }
}

// ---------------- epilogue: relu + fc4, bf16 or fp32 out per flag ----------------
__global__ void out_kernel(const float* __restrict__ hin,
                           const float* __restrict__ W,  // [2, 24]
                           const float* __restrict__ b,  // [2]
                           void* __restrict__ out,
                           const int* __restrict__ flag)
{
    int s = blockIdx.x * blockDim.x + threadIdx.x;
    if (s >= S_LEN) return;
    const int isbf16 = *flag;
    float h[24];
#pragma unroll
    for (int k = 0; k < 24; k++) {
        float v = hin[s * 24 + k];
        h[k] = v > 0.f ? v : 0.f;
    }
#pragma unroll
    for (int j = 0; j < 2; j++) {
        float a = b[j];
#pragma unroll
        for (int k = 0; k < 24; k++) a += W[j * 24 + k] * h[k];
        if (isbf16) ((__hip_bfloat16*)out)[s * 2 + j] = __float2bfloat16(a);
        else        ((float*)out)[s * 2 + j] = a;
    }
}

extern "C" void kernel_launch(void* const* d_in, const int* in_sizes, int n_in,
                              void* d_out, int out_size, void* d_ws, size_t ws_size,
                              hipStream_t stream)
{
    // ---- workspace layout (floats from ws base) ----
    int*   ip    = (int*)d_ws;        // [0]: dtype flag; [256..1280): progress slots
    int*   flag  = ip;
    int*   prog  = ip + 256;
    float* ws    = (float*)d_ws;
    float* conv0 = ws + 4096;

    IngestArgs ia;
    float* conv[N_IN];
    {
        float* p = conv0;
        for (int i = 0; i < N_IN; i++) {
            conv[i] = p;
            ia.src[i] = d_in[i];
            ia.dst[i] = p;
            ia.n[i]   = in_sizes[i];
            p += in_sizes[i];
        }
    }
    float* h2   = conv0 + 191000;       // [S,20]  327,680
    float* seq0 = h2 + 327680;          // 5 x [S,48]
    float* seq1 = seq0 + 786432;
    float* seq2 = seq1 + 786432;
    float* seq3 = seq2 + 786432;
    float* seq4 = seq3 + 786432;
    float* rnnA = seq4 + 786432;        // [S,24]
    float* rnnB = rnnA + 393216;        // [S,24]
    float* rbase = rnnB + 393216;       // rings
    float* ring[7];
    {
        float* p = rbase;
        for (int l = 0; l < 5; l++) { ring[l] = p; p += RING_D * CH2 * 192; }  // 49,152 ea
        for (int l = 5; l < 7; l++) { ring[l] = p; p += RING_D * CH2 * 24;  }  // 6,144 ea
    }

    const int TPB = 256;
    const int NB  = S_LEN / TPB;  // 64

    detect_kernel<<<1, 64, 0, stream>>>(d_in[1], in_sizes[1], flag);
    ingest_kernel<<<128, 256, 0, stream>>>(ia, flag);
    init_kernel<<<1, 1024, 0, stream>>>(prog);

    fc12_kernel<<<NB, TPB, 0, stream>>>(conv[0], conv[1], conv[2], conv[3], conv[4], h2);

    PipeArgs pa;
    pa.h2 = h2;
    pa.l0_Wih = conv[5];  pa.l0_Whh = conv[6];  pa.l0_bih = conv[7];  pa.l0_bhh = conv[8];
    pa.lr_Wih = conv[9];  pa.lr_Whh = conv[10]; pa.lr_bih = conv[11]; pa.lr_bhh = conv[12];
    pa.r0_Wih = conv[13]; pa.r0_Whh = conv[14]; pa.r0_bih = conv[15]; pa.r0_bhh = conv[16];
    pa.r1_Wih = conv[17]; pa.r1_Whh = conv[18]; pa.r1_bih = conv[19]; pa.r1_bhh = conv[20];
    pa.seq0 = seq0; pa.seq1 = seq1; pa.seq2 = seq2; pa.seq3 = seq3; pa.seq4 = seq4;
    pa.rnnA = rnnA; pa.rnnB = rnnB;
    for (int l = 0; l < 7; l++) pa.ring[l] = ring[l];
    pa.prog = prog;

    pipeline_kernel<<<14, 256, 0, stream>>>(pa);

    out_kernel<<<NB, TPB, 0, stream>>>(rnnB, conv[21], conv[22], d_out, flag);
}